// Round 1
// baseline (1016.720 us; speedup 1.0000x reference)
//
#include <hip/hip_runtime.h>

#define NN 100000
#define EE 1600000
#define TT 32
#define DEMB 96
#define DH 128
#define DMLP 256
#define BB 64

// ---------------- init ----------------
__global__ __launch_bounds__(256) void k_init(int* cnt, int* conn, float* sums, float* cntB, int* total, int n) {
    int i = blockIdx.x * 256 + threadIdx.x;
    if (i < n) { cnt[i] = 0; conn[i] = 0; }
    if (i < BB * DH) sums[i] = 0.f;
    if (i < BB) cntB[i] = 0.f;
    if (i == 0) *total = 0;
}

// ---------------- degree count + connected mask ----------------
__global__ __launch_bounds__(256) void k_count(const int* __restrict__ row, const int* __restrict__ col,
                                               int* cnt, int* conn, int e) {
    int i = blockIdx.x * 256 + threadIdx.x;
    if (i >= e) return;
    int r = row[i], c = col[i];
    atomicAdd(&cnt[c], 1);
    conn[r] = 1;
    conn[c] = 1;
}

// ---------------- offset allocation (wave scan + 1 atomic/wave) + dinv ----------------
__global__ __launch_bounds__(256) void k_alloc(const int* __restrict__ cnt, int* off, int* cursor,
                                               float* dinv, int* total, int n) {
    int i = blockIdx.x * 256 + threadIdx.x;
    int lane = threadIdx.x & 63;
    int c = (i < n) ? cnt[i] : 0;
    int s = c;
#pragma unroll
    for (int d = 1; d < 64; d <<= 1) { int t = __shfl_up(s, d); if (lane >= d) s += t; }
    int tot = __shfl(s, 63);
    int base = 0;
    if (lane == 63) base = atomicAdd(total, tot);
    base = __shfl(base, 63);
    int o = base + s - c;  // exclusive prefix + wave base
    if (i < n) {
        off[i] = o;
        cursor[i] = o;
        dinv[i] = 1.0f / sqrtf((float)(1 + c));  // self-loop included
    }
}

// ---------------- scatter edges into CSR (by destination) ----------------
__global__ __launch_bounds__(256) void k_fill(const int* __restrict__ row, const int* __restrict__ col,
                                              int* cursor, int* srcS, float* wS,
                                              const float* __restrict__ dinv, int e) {
    int i = blockIdx.x * 256 + threadIdx.x;
    if (i >= e) return;
    int r = row[i], c = col[i];
    int pos = atomicAdd(&cursor[c], 1);
    srcS[pos] = r;
    wS[pos] = dinv[r] * dinv[c];
}

// ---------------- layer-0 tables: Tm = emb@W0, Tp = emb@P0 + pb0 ----------------
__global__ __launch_bounds__(128) void k_tables(const float* __restrict__ emb, const float* __restrict__ W0,
                                                const float* __restrict__ P0, const float* __restrict__ pb0,
                                                float* Tm, float* Tp) {
    int t = blockIdx.x;      // 0..31
    int j = threadIdx.x;     // 0..127
    float am = 0.f, ap = 0.f;
    for (int k = 0; k < DEMB; k++) {
        float ev = emb[t * DEMB + k];
        am += ev * W0[k * DH + j];
        ap += ev * P0[k * DH + j];
    }
    Tm[t * DH + j] = am;
    Tp[t * DH + j] = ap + pb0[j];
}

// ---------------- layer-0 aggregation (gathers from 32x128 LDS tables) ----------------
__global__ __launch_bounds__(256) void k_agg0(float* __restrict__ H,
                                              const int* __restrict__ srcS, const float* __restrict__ wS,
                                              const int* __restrict__ off, const int* __restrict__ cnt,
                                              const float* __restrict__ dinv, const float* __restrict__ b0,
                                              const int* __restrict__ x,
                                              const float* __restrict__ Tm, const float* __restrict__ Tp, int n) {
    __shared__ float sTm[TT * DH];
    __shared__ float sTp[TT * DH];
    {
        int tid = threadIdx.x;
        for (int i = 0; i < 4; i++) {
            int f = tid + i * 256;  // float4 index over 1024
            ((float4*)sTm)[f] = ((const float4*)Tm)[f];
            ((float4*)sTp)[f] = ((const float4*)Tp)[f];
        }
    }
    __syncthreads();
    int wid = threadIdx.x >> 6, lane = threadIdx.x & 63;
    int node = blockIdx.x * 4 + wid;
    if (node >= n) return;
    int beg = off[node], num = cnt[node];
    float a0 = 0.f, a1 = 0.f;
    for (int i = 0; i < num; i++) {
        int s = srcS[beg + i];
        float w = wS[beg + i];
        const float* mr = &sTm[x[s] * DH];
        a0 += w * mr[lane];
        a1 += w * mr[64 + lane];
    }
    float di = dinv[node];
    float wl = di * di;
    const float* mc = &sTm[x[node] * DH];
    a0 += wl * mc[lane];
    a1 += wl * mc[64 + lane];
    a0 += b0[lane];
    a1 += b0[64 + lane];
    const float* pc = &sTp[x[node] * DH];
    float r0 = 0.5f * pc[lane] + 0.5f * a0;
    float r1 = 0.5f * pc[64 + lane] + 0.5f * a1;
    r0 = fmaxf(r0, 0.f);
    r1 = fmaxf(r1, 0.f);
    H[(size_t)node * DH + lane] = r0;
    H[(size_t)node * DH + 64 + lane] = r1;
}

// ---------------- layers 1/2 aggregation (in-place on H, gathers from M) ----------------
template <int RELU>
__global__ __launch_bounds__(256) void k_agg(const float* __restrict__ M, float* __restrict__ H,
                                             const int* __restrict__ srcS, const float* __restrict__ wS,
                                             const int* __restrict__ off, const int* __restrict__ cnt,
                                             const float* __restrict__ dinv, const float* __restrict__ bias, int n) {
    int wid = threadIdx.x >> 6, lane = threadIdx.x & 63;
    int node = blockIdx.x * 4 + wid;
    if (node >= n) return;
    int beg = off[node], num = cnt[node];
    float a0 = 0.f, a1 = 0.f;
    for (int i = 0; i < num; i++) {
        int s = srcS[beg + i];
        float w = wS[beg + i];
        const float* mr = &M[(size_t)s * DH];
        a0 += w * mr[lane];
        a1 += w * mr[64 + lane];
    }
    float di = dinv[node];
    float wl = di * di;
    const float* mc = &M[(size_t)node * DH];
    a0 += wl * mc[lane];
    a1 += wl * mc[64 + lane];
    a0 += bias[lane];
    a1 += bias[64 + lane];
    size_t hb = (size_t)node * DH;
    float r0 = 0.5f * H[hb + lane] + 0.5f * a0;
    float r1 = 0.5f * H[hb + 64 + lane] + 0.5f * a1;
    if (RELU) { r0 = fmaxf(r0, 0.f); r1 = fmaxf(r1, 0.f); }
    H[hb + lane] = r0;
    H[hb + 64 + lane] = r1;
}

// ---------------- fp32 GEMM: C[n x 128] = A[n x 128] @ W[128 x 128] ----------------
__global__ __launch_bounds__(256) void k_gemm(const float* __restrict__ A, const float* __restrict__ W,
                                              float* __restrict__ C, int n) {
    __shared__ float sA[128 * 132];  // padded stride 132
    __shared__ float sW[128 * 128];
    int tid = threadIdx.x;
    int base = blockIdx.x * 128;
    for (int i = 0; i < 16; i++) {
        int f = tid + i * 256;
        ((float4*)sW)[f] = ((const float4*)W)[f];
    }
    for (int i = 0; i < 16; i++) {
        int f = tid + i * 256;    // float4 idx, 32 per row
        int r = f >> 5, c4 = f & 31;
        int gr = base + r;
        float4 v = make_float4(0.f, 0.f, 0.f, 0.f);
        if (gr < n) v = *((const float4*)&A[(size_t)gr * DH + c4 * 4]);
        *((float4*)&sA[r * 132 + c4 * 4]) = v;
    }
    __syncthreads();
    int ty = tid >> 4, tx = tid & 15;
    int r0 = ty * 8, c0 = tx * 8;
    float acc[8][8];
#pragma unroll
    for (int i = 0; i < 8; i++)
#pragma unroll
        for (int j = 0; j < 8; j++) acc[i][j] = 0.f;

    for (int k = 0; k < 128; k += 4) {
        float4 a[8];
        float4 b[8];
#pragma unroll
        for (int i = 0; i < 8; i++) a[i] = *((float4*)&sA[(r0 + i) * 132 + k]);
#pragma unroll
        for (int kk = 0; kk < 4; kk++) {
            b[kk * 2]     = *((float4*)&sW[(k + kk) * 128 + c0]);
            b[kk * 2 + 1] = *((float4*)&sW[(k + kk) * 128 + c0 + 4]);
        }
#pragma unroll
        for (int i = 0; i < 8; i++) {
            float av[4] = {a[i].x, a[i].y, a[i].z, a[i].w};
#pragma unroll
            for (int kk = 0; kk < 4; kk++) {
                float4 b0v = b[kk * 2], b1v = b[kk * 2 + 1];
                acc[i][0] += av[kk] * b0v.x;
                acc[i][1] += av[kk] * b0v.y;
                acc[i][2] += av[kk] * b0v.z;
                acc[i][3] += av[kk] * b0v.w;
                acc[i][4] += av[kk] * b1v.x;
                acc[i][5] += av[kk] * b1v.y;
                acc[i][6] += av[kk] * b1v.z;
                acc[i][7] += av[kk] * b1v.w;
            }
        }
    }
#pragma unroll
    for (int i = 0; i < 8; i++) {
        int gr = base + r0 + i;
        if (gr < n) {
            float4 v0 = make_float4(acc[i][0], acc[i][1], acc[i][2], acc[i][3]);
            float4 v1 = make_float4(acc[i][4], acc[i][5], acc[i][6], acc[i][7]);
            *((float4*)&C[(size_t)gr * DH + c0]) = v0;
            *((float4*)&C[(size_t)gr * DH + c0 + 4]) = v1;
        }
    }
}

// ---------------- pooling ----------------
__device__ inline int lbound(const int* a, int n, int v) {
    int lo = 0, hi = n;
    while (lo < hi) {
        int mid = (lo + hi) >> 1;
        if (a[mid] < v) lo = mid + 1; else hi = mid;
    }
    return lo;
}

__global__ __launch_bounds__(128) void k_pool(const float* __restrict__ H, const int* __restrict__ conn,
                                              const int* __restrict__ batch, float* sums, float* cntB, int n) {
    int b = blockIdx.x >> 3;
    int s = blockIdx.x & 7;
    int start = lbound(batch, n, b);
    int end = lbound(batch, n, b + 1);
    int d = threadIdx.x;
    float acc = 0.f, c = 0.f;
    for (int i = start + s; i < end; i += 8) {
        if (conn[i]) {
            acc += H[(size_t)i * DH + d];
            c += 1.f;
        }
    }
    atomicAdd(&sums[b * DH + d], acc);
    if (d == 0) atomicAdd(&cntB[b], c);
}

// ---------------- MLP head ----------------
__global__ __launch_bounds__(256) void k_mlp(const float* __restrict__ sums, const float* __restrict__ cntB,
                                             const float* __restrict__ M1, const float* __restrict__ mb1,
                                             const float* __restrict__ M2, const float* __restrict__ mb2,
                                             float* out) {
    int b = blockIdx.x;
    int j = threadIdx.x;
    __shared__ float g[DH];
    __shared__ float red[DMLP];
    float inv = 1.0f / fmaxf(cntB[b], 1.0f);
    if (j < DH) g[j] = sums[b * DH + j] * inv;
    __syncthreads();
    float acc = mb1[j];
    for (int k = 0; k < DH; k++) acc += g[k] * M1[k * DMLP + j];
    float v = fmaxf(acc, 0.f) * M2[j];
    red[j] = v;
    __syncthreads();
    for (int sdiv = 128; sdiv > 0; sdiv >>= 1) {
        if (j < sdiv) red[j] += red[j + sdiv];
        __syncthreads();
    }
    if (j == 0) out[b] = red[0] + mb2[0];
}

// ---------------- launch ----------------
extern "C" void kernel_launch(void* const* d_in, const int* in_sizes, int n_in,
                              void* d_out, int out_size, void* d_ws, size_t ws_size,
                              hipStream_t stream) {
    const int* x      = (const int*)d_in[0];
    const int* ei     = (const int*)d_in[1];
    const int* batch  = (const int*)d_in[2];
    const float* emb  = (const float*)d_in[3];
    const float* W0   = (const float*)d_in[4];
    const float* b0   = (const float*)d_in[5];
    const float* W1   = (const float*)d_in[6];
    const float* b1   = (const float*)d_in[7];
    const float* W2   = (const float*)d_in[8];
    const float* b2   = (const float*)d_in[9];
    const float* P0   = (const float*)d_in[10];
    const float* pb0  = (const float*)d_in[11];
    const float* M1   = (const float*)d_in[12];
    const float* mb1  = (const float*)d_in[13];
    const float* M2   = (const float*)d_in[14];
    const float* mb2  = (const float*)d_in[15];
    float* out = (float*)d_out;

    const int* row = ei;
    const int* col = ei + EE;

    char* p = (char*)d_ws;
    auto alloc = [&](size_t bytes) {
        void* q = (void*)p;
        p += (bytes + 255) & ~(size_t)255;
        return q;
    };
    int* cnt      = (int*)alloc(NN * 4);
    int* off      = (int*)alloc(NN * 4);
    int* cursor   = (int*)alloc(NN * 4);
    int* conn     = (int*)alloc(NN * 4);
    float* dinv   = (float*)alloc(NN * 4);
    int* total    = (int*)alloc(256);
    int* srcS     = (int*)alloc((size_t)EE * 4);
    float* wS     = (float*)alloc((size_t)EE * 4);
    float* Tm     = (float*)alloc(TT * DH * 4);
    float* Tp     = (float*)alloc(TT * DH * 4);
    float* H      = (float*)alloc((size_t)NN * DH * 4);
    float* M      = (float*)alloc((size_t)NN * DH * 4);
    float* sums   = (float*)alloc(BB * DH * 4);
    float* cntB   = (float*)alloc(BB * 4);

    int gN = (NN + 255) / 256;
    int gE = (EE + 255) / 256;

    k_init<<<gN, 256, 0, stream>>>(cnt, conn, sums, cntB, total, NN);
    k_count<<<gE, 256, 0, stream>>>(row, col, cnt, conn, EE);
    k_alloc<<<gN, 256, 0, stream>>>(cnt, off, cursor, dinv, total, NN);
    k_fill<<<gE, 256, 0, stream>>>(row, col, cursor, srcS, wS, dinv, EE);
    k_tables<<<TT, 128, 0, stream>>>(emb, W0, P0, pb0, Tm, Tp);
    k_agg0<<<(NN + 3) / 4, 256, 0, stream>>>(H, srcS, wS, off, cnt, dinv, b0, x, Tm, Tp, NN);
    k_gemm<<<(NN + 127) / 128, 256, 0, stream>>>(H, W1, M, NN);
    k_agg<1><<<(NN + 3) / 4, 256, 0, stream>>>(M, H, srcS, wS, off, cnt, dinv, b1, NN);
    k_gemm<<<(NN + 127) / 128, 256, 0, stream>>>(H, W2, M, NN);
    k_agg<0><<<(NN + 3) / 4, 256, 0, stream>>>(M, H, srcS, wS, off, cnt, dinv, b2, NN);
    k_pool<<<BB * 8, 128, 0, stream>>>(H, conn, batch, sums, cntB, NN);
    k_mlp<<<BB, 256, 0, stream>>>(sums, cntB, M1, mb1, M2, mb2, out);
}

// Round 2
// 848.612 us; speedup vs baseline: 1.1981x; 1.1981x over previous
//
#include <hip/hip_runtime.h>

#define NN 100000
#define EE 1600000
#define TT 32
#define DEMB 96
#define DH 128
#define DMLP 256
#define BB 64

// ---------------- init ----------------
__global__ __launch_bounds__(256) void k_init(int* cnt, int* conn, float* sums, float* cntB, int* total, int n) {
    int i = blockIdx.x * 256 + threadIdx.x;
    if (i < n) { cnt[i] = 0; conn[i] = 0; }
    if (i < BB * DH) sums[i] = 0.f;
    if (i < BB) cntB[i] = 0.f;
    if (i == 0) *total = 0;
}

// ---------------- degree count + connected mask ----------------
__global__ __launch_bounds__(256) void k_count(const int* __restrict__ row, const int* __restrict__ col,
                                               int* cnt, int* conn, int e) {
    int i = blockIdx.x * 256 + threadIdx.x;
    if (i >= e) return;
    int r = row[i], c = col[i];
    atomicAdd(&cnt[c], 1);
    conn[r] = 1;
    conn[c] = 1;
}

// ---------------- offset allocation (wave scan + 1 atomic/wave) + dinv ----------------
__global__ __launch_bounds__(256) void k_alloc(const int* __restrict__ cnt, int* off, int* cursor,
                                               float* dinv, int* total, int n) {
    int i = blockIdx.x * 256 + threadIdx.x;
    int lane = threadIdx.x & 63;
    int c = (i < n) ? cnt[i] : 0;
    int s = c;
#pragma unroll
    for (int d = 1; d < 64; d <<= 1) { int t = __shfl_up(s, d); if (lane >= d) s += t; }
    int tot = __shfl(s, 63);
    int base = 0;
    if (lane == 63) base = atomicAdd(total, tot);
    base = __shfl(base, 63);
    int o = base + s - c;  // exclusive prefix + wave base
    if (i < n) {
        off[i] = o;
        cursor[i] = o;
        dinv[i] = 1.0f / sqrtf((float)(1 + c));  // self-loop included
    }
}

// ---------------- scatter edges into CSR (by destination) ----------------
__global__ __launch_bounds__(256) void k_fill(const int* __restrict__ row, const int* __restrict__ col,
                                              int* cursor, int* srcS, float* wS,
                                              const float* __restrict__ dinv, int e) {
    int i = blockIdx.x * 256 + threadIdx.x;
    if (i >= e) return;
    int r = row[i], c = col[i];
    int pos = atomicAdd(&cursor[c], 1);
    srcS[pos] = r;
    wS[pos] = dinv[r] * dinv[c];
}

// ---------------- layer-0 tables: Tm = emb@W0, Tp = emb@P0 + pb0 ----------------
__global__ __launch_bounds__(128) void k_tables(const float* __restrict__ emb, const float* __restrict__ W0,
                                                const float* __restrict__ P0, const float* __restrict__ pb0,
                                                float* Tm, float* Tp) {
    int t = blockIdx.x;      // 0..31
    int j = threadIdx.x;     // 0..127
    float am = 0.f, ap = 0.f;
    for (int k = 0; k < DEMB; k++) {
        float ev = emb[t * DEMB + k];
        am += ev * W0[k * DH + j];
        ap += ev * P0[k * DH + j];
    }
    Tm[t * DH + j] = am;
    Tp[t * DH + j] = ap + pb0[j];
}

// ---------------- layer-0 aggregation via per-node type bincount ----------------
// h0 = Tm[x] is rank-32: agg(h0)[node] = sum_t bin[node][t] * Tm[t]
// bin[t] = sum over incoming edges with x[src]==t of w_e (+ self-loop weight).
__global__ __launch_bounds__(256) void k_agg0(float* __restrict__ H,
                                              const int* __restrict__ srcS, const float* __restrict__ wS,
                                              const int* __restrict__ off, const int* __restrict__ cnt,
                                              const float* __restrict__ dinv, const float* __restrict__ b0,
                                              const int* __restrict__ x,
                                              const float* __restrict__ Tm, const float* __restrict__ Tp, int n) {
    __shared__ float sTm[TT * DH];
    __shared__ float sTp[TT * DH];
    __shared__ float bins[4][TT];
    int tid = threadIdx.x;
    for (int i = 0; i < 4; i++) {
        int f = tid + i * 256;  // float4 index over 1024
        ((float4*)sTm)[f] = ((const float4*)Tm)[f];
        ((float4*)sTp)[f] = ((const float4*)Tp)[f];
    }
    int wid = tid >> 6, lane = tid & 63;
    if (lane < TT) bins[wid][lane] = 0.f;
    __syncthreads();

    int node = blockIdx.x * 4 + wid;
    bool valid = node < n;
    int beg = 0, num = 0, xn = 0;
    if (valid) { beg = off[node]; num = cnt[node]; xn = x[node]; }
    // edges distributed across lanes: coalesced meta reads, one 4B gather of x[s]
    for (int i = lane; i < num; i += 64) {
        int s = srcS[beg + i];
        float w = wS[beg + i];
        atomicAdd(&bins[wid][x[s]], w);
    }
    if (valid && lane == 0) {
        float di = dinv[node];
        atomicAdd(&bins[wid][xn], di * di);
    }
    __syncthreads();
    if (!valid) return;

    float a0 = 0.f, a1 = 0.f;  // features lane*2, lane*2+1
#pragma unroll
    for (int t = 0; t < TT; t++) {
        float w = bins[wid][t];
        float2 tm = *((const float2*)&sTm[t * DH + lane * 2]);
        a0 += w * tm.x;
        a1 += w * tm.y;
    }
    float2 bb = *((const float2*)&b0[lane * 2]);
    a0 += bb.x;
    a1 += bb.y;
    float2 pp = *((const float2*)&sTp[xn * DH + lane * 2]);
    float r0 = 0.5f * pp.x + 0.5f * a0;
    float r1 = 0.5f * pp.y + 0.5f * a1;
    r0 = fmaxf(r0, 0.f);
    r1 = fmaxf(r1, 0.f);
    *((float2*)&H[(size_t)node * DH + lane * 2]) = make_float2(r0, r1);
}

// ---------------- layers 1/2 aggregation (in-place on H, gathers from M) ----------------
// One wave per node, 2 features/lane (float2), edges unrolled x4 for memory-level parallelism.
template <int RELU>
__global__ __launch_bounds__(256) void k_agg(const float* __restrict__ M, float* __restrict__ H,
                                             const int* __restrict__ srcS, const float* __restrict__ wS,
                                             const int* __restrict__ off, const int* __restrict__ cnt,
                                             const float* __restrict__ dinv, const float* __restrict__ bias, int n) {
    int wid = threadIdx.x >> 6, lane = threadIdx.x & 63;
    int node = blockIdx.x * 4 + wid;
    if (node >= n) return;
    int beg = off[node], num = cnt[node];
    int fo = lane * 2;  // feature offset for this lane
    float a0 = 0.f, a1 = 0.f;
    int i = 0;
    for (; i + 4 <= num; i += 4) {
        int s0 = srcS[beg + i];
        int s1 = srcS[beg + i + 1];
        int s2 = srcS[beg + i + 2];
        int s3 = srcS[beg + i + 3];
        float w0 = wS[beg + i];
        float w1 = wS[beg + i + 1];
        float w2 = wS[beg + i + 2];
        float w3 = wS[beg + i + 3];
        float2 v0 = *((const float2*)&M[(size_t)s0 * DH + fo]);
        float2 v1 = *((const float2*)&M[(size_t)s1 * DH + fo]);
        float2 v2 = *((const float2*)&M[(size_t)s2 * DH + fo]);
        float2 v3 = *((const float2*)&M[(size_t)s3 * DH + fo]);
        a0 += w0 * v0.x;
        a1 += w0 * v0.y;
        a0 += w1 * v1.x;
        a1 += w1 * v1.y;
        a0 += w2 * v2.x;
        a1 += w2 * v2.y;
        a0 += w3 * v3.x;
        a1 += w3 * v3.y;
    }
    for (; i < num; i++) {
        int s = srcS[beg + i];
        float w = wS[beg + i];
        float2 v = *((const float2*)&M[(size_t)s * DH + fo]);
        a0 += w * v.x;
        a1 += w * v.y;
    }
    float di = dinv[node];
    float wl = di * di;
    float2 vc = *((const float2*)&M[(size_t)node * DH + fo]);
    a0 += wl * vc.x;
    a1 += wl * vc.y;
    float2 bb = *((const float2*)&bias[fo]);
    a0 += bb.x;
    a1 += bb.y;
    size_t hb = (size_t)node * DH + fo;
    float2 h = *((float2*)&H[hb]);
    float r0 = 0.5f * h.x + 0.5f * a0;
    float r1 = 0.5f * h.y + 0.5f * a1;
    if (RELU) { r0 = fmaxf(r0, 0.f); r1 = fmaxf(r1, 0.f); }
    *((float2*)&H[hb]) = make_float2(r0, r1);
}

// ---------------- fp32 GEMM: C[n x 128] = A[n x 128] @ W[128 x 128] ----------------
__global__ __launch_bounds__(256) void k_gemm(const float* __restrict__ A, const float* __restrict__ W,
                                              float* __restrict__ C, int n) {
    __shared__ float sA[128 * 132];  // padded stride 132
    __shared__ float sW[128 * 128];
    int tid = threadIdx.x;
    int base = blockIdx.x * 128;
    for (int i = 0; i < 16; i++) {
        int f = tid + i * 256;
        ((float4*)sW)[f] = ((const float4*)W)[f];
    }
    for (int i = 0; i < 16; i++) {
        int f = tid + i * 256;    // float4 idx, 32 per row
        int r = f >> 5, c4 = f & 31;
        int gr = base + r;
        float4 v = make_float4(0.f, 0.f, 0.f, 0.f);
        if (gr < n) v = *((const float4*)&A[(size_t)gr * DH + c4 * 4]);
        *((float4*)&sA[r * 132 + c4 * 4]) = v;
    }
    __syncthreads();
    int ty = tid >> 4, tx = tid & 15;
    int r0 = ty * 8, c0 = tx * 8;
    float acc[8][8];
#pragma unroll
    for (int i = 0; i < 8; i++)
#pragma unroll
        for (int j = 0; j < 8; j++) acc[i][j] = 0.f;

    for (int k = 0; k < 128; k += 4) {
        float4 a[8];
        float4 b[8];
#pragma unroll
        for (int i = 0; i < 8; i++) a[i] = *((float4*)&sA[(r0 + i) * 132 + k]);
#pragma unroll
        for (int kk = 0; kk < 4; kk++) {
            b[kk * 2]     = *((float4*)&sW[(k + kk) * 128 + c0]);
            b[kk * 2 + 1] = *((float4*)&sW[(k + kk) * 128 + c0 + 4]);
        }
#pragma unroll
        for (int i = 0; i < 8; i++) {
            float av[4] = {a[i].x, a[i].y, a[i].z, a[i].w};
#pragma unroll
            for (int kk = 0; kk < 4; kk++) {
                float4 b0v = b[kk * 2], b1v = b[kk * 2 + 1];
                acc[i][0] += av[kk] * b0v.x;
                acc[i][1] += av[kk] * b0v.y;
                acc[i][2] += av[kk] * b0v.z;
                acc[i][3] += av[kk] * b0v.w;
                acc[i][4] += av[kk] * b1v.x;
                acc[i][5] += av[kk] * b1v.y;
                acc[i][6] += av[kk] * b1v.z;
                acc[i][7] += av[kk] * b1v.w;
            }
        }
    }
#pragma unroll
    for (int i = 0; i < 8; i++) {
        int gr = base + r0 + i;
        if (gr < n) {
            float4 v0 = make_float4(acc[i][0], acc[i][1], acc[i][2], acc[i][3]);
            float4 v1 = make_float4(acc[i][4], acc[i][5], acc[i][6], acc[i][7]);
            *((float4*)&C[(size_t)gr * DH + c0]) = v0;
            *((float4*)&C[(size_t)gr * DH + c0 + 4]) = v1;
        }
    }
}

// ---------------- pooling ----------------
__device__ inline int lbound(const int* a, int n, int v) {
    int lo = 0, hi = n;
    while (lo < hi) {
        int mid = (lo + hi) >> 1;
        if (a[mid] < v) lo = mid + 1; else hi = mid;
    }
    return lo;
}

__global__ __launch_bounds__(128) void k_pool(const float* __restrict__ H, const int* __restrict__ conn,
                                              const int* __restrict__ batch, float* sums, float* cntB, int n) {
    int b = blockIdx.x >> 3;
    int s = blockIdx.x & 7;
    int start = lbound(batch, n, b);
    int end = lbound(batch, n, b + 1);
    int d = threadIdx.x;
    float acc = 0.f, c = 0.f;
    for (int i = start + s; i < end; i += 8) {
        if (conn[i]) {
            acc += H[(size_t)i * DH + d];
            c += 1.f;
        }
    }
    atomicAdd(&sums[b * DH + d], acc);
    if (d == 0) atomicAdd(&cntB[b], c);
}

// ---------------- MLP head ----------------
__global__ __launch_bounds__(256) void k_mlp(const float* __restrict__ sums, const float* __restrict__ cntB,
                                             const float* __restrict__ M1, const float* __restrict__ mb1,
                                             const float* __restrict__ M2, const float* __restrict__ mb2,
                                             float* out) {
    int b = blockIdx.x;
    int j = threadIdx.x;
    __shared__ float g[DH];
    __shared__ float red[DMLP];
    float inv = 1.0f / fmaxf(cntB[b], 1.0f);
    if (j < DH) g[j] = sums[b * DH + j] * inv;
    __syncthreads();
    float acc = mb1[j];
    for (int k = 0; k < DH; k++) acc += g[k] * M1[k * DMLP + j];
    float v = fmaxf(acc, 0.f) * M2[j];
    red[j] = v;
    __syncthreads();
    for (int sdiv = 128; sdiv > 0; sdiv >>= 1) {
        if (j < sdiv) red[j] += red[j + sdiv];
        __syncthreads();
    }
    if (j == 0) out[b] = red[0] + mb2[0];
}

// ---------------- launch ----------------
extern "C" void kernel_launch(void* const* d_in, const int* in_sizes, int n_in,
                              void* d_out, int out_size, void* d_ws, size_t ws_size,
                              hipStream_t stream) {
    const int* x      = (const int*)d_in[0];
    const int* ei     = (const int*)d_in[1];
    const int* batch  = (const int*)d_in[2];
    const float* emb  = (const float*)d_in[3];
    const float* W0   = (const float*)d_in[4];
    const float* b0   = (const float*)d_in[5];
    const float* W1   = (const float*)d_in[6];
    const float* b1   = (const float*)d_in[7];
    const float* W2   = (const float*)d_in[8];
    const float* b2   = (const float*)d_in[9];
    const float* P0   = (const float*)d_in[10];
    const float* pb0  = (const float*)d_in[11];
    const float* M1   = (const float*)d_in[12];
    const float* mb1  = (const float*)d_in[13];
    const float* M2   = (const float*)d_in[14];
    const float* mb2  = (const float*)d_in[15];
    float* out = (float*)d_out;

    const int* row = ei;
    const int* col = ei + EE;

    char* p = (char*)d_ws;
    auto alloc = [&](size_t bytes) {
        void* q = (void*)p;
        p += (bytes + 255) & ~(size_t)255;
        return q;
    };
    int* cnt      = (int*)alloc(NN * 4);
    int* off      = (int*)alloc(NN * 4);
    int* cursor   = (int*)alloc(NN * 4);
    int* conn     = (int*)alloc(NN * 4);
    float* dinv   = (float*)alloc(NN * 4);
    int* total    = (int*)alloc(256);
    int* srcS     = (int*)alloc((size_t)EE * 4);
    float* wS     = (float*)alloc((size_t)EE * 4);
    float* Tm     = (float*)alloc(TT * DH * 4);
    float* Tp     = (float*)alloc(TT * DH * 4);
    float* H      = (float*)alloc((size_t)NN * DH * 4);
    float* M      = (float*)alloc((size_t)NN * DH * 4);
    float* sums   = (float*)alloc(BB * DH * 4);
    float* cntB   = (float*)alloc(BB * 4);

    int gN = (NN + 255) / 256;
    int gE = (EE + 255) / 256;

    k_init<<<gN, 256, 0, stream>>>(cnt, conn, sums, cntB, total, NN);
    k_count<<<gE, 256, 0, stream>>>(row, col, cnt, conn, EE);
    k_alloc<<<gN, 256, 0, stream>>>(cnt, off, cursor, dinv, total, NN);
    k_fill<<<gE, 256, 0, stream>>>(row, col, cursor, srcS, wS, dinv, EE);
    k_tables<<<TT, 128, 0, stream>>>(emb, W0, P0, pb0, Tm, Tp);
    k_agg0<<<(NN + 3) / 4, 256, 0, stream>>>(H, srcS, wS, off, cnt, dinv, b0, x, Tm, Tp, NN);
    k_gemm<<<(NN + 127) / 128, 256, 0, stream>>>(H, W1, M, NN);
    k_agg<1><<<(NN + 3) / 4, 256, 0, stream>>>(M, H, srcS, wS, off, cnt, dinv, b1, NN);
    k_gemm<<<(NN + 127) / 128, 256, 0, stream>>>(H, W2, M, NN);
    k_agg<0><<<(NN + 3) / 4, 256, 0, stream>>>(M, H, srcS, wS, off, cnt, dinv, b2, NN);
    k_pool<<<BB * 8, 128, 0, stream>>>(H, conn, batch, sums, cntB, NN);
    k_mlp<<<BB, 256, 0, stream>>>(sums, cntB, M1, mb1, M2, mb2, out);
}